// Round 5
// baseline (125.589 us; speedup 1.0000x reference)
//
#include <hip/hip_runtime.h>
#include <math.h>

#define NCH 32
#define HALF 17
#define RPB 64      // rows per block = exactly one wave (no inter-wave barriers)
#define PAD 33      // LDS row pitch (floats): (t*33+c)%32 = (t+c)%32 -> conflict-free

typedef float f32x4 __attribute__((ext_vector_type(4)));

// cos(2*pi*j/32), sin(2*pi*j/32)
constexpr float CT[32] = {
   1.0f,                 0.9807852804032304f,  0.9238795325112867f,  0.8314696123025452f,
   0.7071067811865476f,  0.5555702330196022f,  0.3826834323650898f,  0.1950903220161283f,
   0.0f,                -0.1950903220161283f, -0.3826834323650898f, -0.5555702330196022f,
  -0.7071067811865476f, -0.8314696123025452f, -0.9238795325112867f, -0.9807852804032304f,
  -1.0f,                -0.9807852804032304f, -0.9238795325112867f, -0.8314696123025452f,
  -0.7071067811865476f, -0.5555702330196022f, -0.3826834323650898f, -0.1950903220161283f,
   0.0f,                 0.1950903220161283f,  0.3826834323650898f,  0.5555702330196022f,
   0.7071067811865476f,  0.8314696123025452f,  0.9238795325112867f,  0.9807852804032304f
};
constexpr float ST[32] = {
   0.0f,                 0.1950903220161283f,  0.3826834323650898f,  0.5555702330196022f,
   0.7071067811865476f,  0.8314696123025452f,  0.9238795325112867f,  0.9807852804032304f,
   1.0f,                 0.9807852804032304f,  0.9238795325112867f,  0.8314696123025452f,
   0.7071067811865476f,  0.5555702330196022f,  0.3826834323650898f,  0.1950903220161283f,
   0.0f,                -0.1950903220161283f, -0.3826834323650898f, -0.5555702330196022f,
  -0.7071067811865476f, -0.8314696123025452f, -0.9238795325112867f, -0.9807852804032304f,
  -1.0f,                -0.9807852804032304f, -0.9238795325112867f, -0.8314696123025452f,
  -0.7071067811865476f, -0.5555702330196022f, -0.3826834323650898f, -0.1950903220161283f
};

// Complex nonlinearity for one bin. Bin value X = inv*(sr - i*si); the forward
// 1/sqrt(32) is pre-folded into (w1r,w1i); the inverse scale (2*inv for k=1..15,
// inv for DC/Nyquist) AND the 0.5 of cosh/sinh are pre-folded into (w2r,w2i).
__device__ __forceinline__ void cnonlin(float sr, float si,
    float w1r, float w1i, float w2r, float w2i, float& G, float& H)
{
    const float p = fmaf(sr, w1r, si * w1i);        // Re(X*cm1)   (note Xim = -inv*si)
    const float q = fmaf(sr, w1i, -(si * w1r));     // Im(X*cm1)
    float sp, cp;
    __sincosf(p, &sp, &cp);
    const float eq = __expf(q), en = __expf(-q);
    const float sA = sp * (eq + en);                // 2*sin(p)*cosh(q)
    const float sB = cp * (eq - en);                // 2*cos(p)*sinh(q)
    G = fmaf(sA, w2r, -(sB * w2i));
    H = fmaf(sA, w2i, sB * w2r);
}

// DC/Nyquist bins: si == 0 on input, and irfft only consumes the real part.
__device__ __forceinline__ float cnonlin_real(float sr,
    float w1r, float w1i, float w2r, float w2i)
{
    const float p = sr * w1r;
    const float q = sr * w1i;
    float sp, cp;
    __sincosf(p, &sp, &cp);
    const float eq = __expf(q), en = __expf(-q);
    return fmaf(sp * (eq + en), w2r, -((cp * (eq - en)) * w2i));
}

__global__ __launch_bounds__(RPB) void fcm_kernel(
    const float* __restrict__ x,
    const float* __restrict__ c1r, const float* __restrict__ c1i,
    const float* __restrict__ c2r, const float* __restrict__ c2i,
    float* __restrict__ out)
{
    __shared__ float tile[RPB * PAD];
    const int t = threadIdx.x;
    const long long base = (long long)blockIdx.x * (RPB * NCH);
    const float inv = 0.17677669529663687f;          // 1/sqrt(32)

    // ---- coalesced global -> LDS staging (nontemporal float4 per lane) ----
    #pragma unroll
    for (int i = 0; i < 8; ++i) {
        const int ft = (i * RPB + t) * 4;
        f32x4 v = __builtin_nontemporal_load(
            reinterpret_cast<const f32x4*>(x + base + ft));
        const int row = ft >> 5, col = ft & 31;
        float* p = &tile[row * PAD + col];
        p[0] = v.x; p[1] = v.y; p[2] = v.z; p[3] = v.w;
    }
    __syncthreads();

    // ---- each thread owns one row of 32 channels ----
    float xr[NCH];
    #pragma unroll
    for (int j = 0; j < NCH; ++j) xr[j] = tile[t * PAD + j];

    // symmetric combos (halves the DFT inner loops)
    float ev[16], od[16];
    #pragma unroll
    for (int m = 1; m <= 15; ++m) {
        ev[m] = xr[m] + xr[32 - m];
        od[m] = xr[m] - xr[32 - m];
    }
    const float xp = xr[0] + xr[16], xm = xr[0] - xr[16];
    const float e8 = ev[8], o8 = od[8];
    float ep[8], em[8], opp[8], om[8];               // m = 1..7 used
    #pragma unroll
    for (int m = 1; m <= 7; ++m) {
        ep[m]  = ev[m] + ev[16 - m];
        em[m]  = ev[m] - ev[16 - m];
        opp[m] = od[m] + od[16 - m];
        om[m]  = od[m] - od[16 - m];
    }

    // ---- forward DFT (streamed) + nonlinearity -> combined inverse inputs ----
    float Gp[8], Gm[8], Hp[8], Hm[8];
    float G0, G16, G8, H8;

    {   // specials k = 0, 16, 8 (bins 0/16 real; Xim unused by irfft there)
        const float A  = ep[2] + ep[4] + ep[6];
        const float B  = ep[1] + ep[3] + ep[5] + ep[7];
        const float b0 = xp + e8;
        const float sr0  = b0 + A + B;
        const float sr16 = b0 + A - B;
        G0  = cnonlin_real(sr0,  c1r[0]  * inv, c1i[0]  * inv,
                           c2r[0]  * (0.5f * inv), c2i[0]  * (0.5f * inv));
        G16 = cnonlin_real(sr16, c1r[16] * inv, c1i[16] * inv,
                           c2r[16] * (0.5f * inv), c2i[16] * (0.5f * inv));
        const float sr8 = b0 - ep[2] + ep[4] - ep[6];
        const float si8 = om[1] - om[3] + om[5] - om[7];
        cnonlin(sr8, si8, c1r[8] * inv, c1i[8] * inv,
                c2r[8] * inv, c2i[8] * inv, G8, H8);
    }

    // pairs (k, 16-k), k = 1..7: shared even-m/odd-m partial sums serve both bins
    #pragma unroll
    for (int k = 1; k <= 7; ++k) {
        const int kp = 16 - k;
        const bool kodd = (k & 1);
        const float u1 = kodd ? em[1] : ep[1],  u3 = kodd ? em[3] : ep[3];
        const float u5 = kodd ? em[5] : ep[5],  u7 = kodd ? em[7] : ep[7];
        const float u2 = kodd ? em[2] : ep[2],  u4 = kodd ? em[4] : ep[4];
        const float u6 = kodd ? em[6] : ep[6];
        const float v1 = kodd ? opp[1] : om[1], v3 = kodd ? opp[3] : om[3];
        const float v5 = kodd ? opp[5] : om[5], v7 = kodd ? opp[7] : om[7];
        const float v2 = kodd ? opp[2] : om[2], v4 = kodd ? opp[4] : om[4];
        const float v6 = kodd ? opp[6] : om[6];

        const float SrE = fmaf(CT[(2*k)&31], u2, fmaf(CT[(4*k)&31], u4, CT[(6*k)&31] * u6));
        const float SrO = fmaf(CT[k&31], u1, fmaf(CT[(3*k)&31], u3,
                          fmaf(CT[(5*k)&31], u5, CT[(7*k)&31] * u7)));
        const float SiE = fmaf(ST[(2*k)&31], v2, fmaf(ST[(4*k)&31], v4, ST[(6*k)&31] * v6));
        const float SiO = fmaf(ST[k&31], v1, fmaf(ST[(3*k)&31], v3,
                          fmaf(ST[(5*k)&31], v5, ST[(7*k)&31] * v7)));

        // base: odd k -> x0-x16 (cos(pi*k/2)=0); even k -> x0+x16 +/- e8
        const float tb = kodd ? xm : (xp + (((k & 2) == 0) ? e8 : -e8));
        float SiEO  = SiE + SiO;
        float SiOmE = SiO - SiE;
        if (kodd) {                                   // sin(pi*k/2)*o8 term
            const float s8 = ((k & 2) == 0) ? o8 : -o8;
            SiEO  += s8;
            SiOmE -= s8;
        }
        const float srk  = tb + SrE + SrO;
        const float srkp = tb + (SrE - SrO);

        float Gk, Hk, Gkp, Hkp;
        cnonlin(srk,  SiEO,  c1r[k]  * inv, c1i[k]  * inv,
                c2r[k]  * inv, c2i[k]  * inv, Gk,  Hk);
        cnonlin(srkp, SiOmE, c1r[kp] * inv, c1i[kp] * inv,
                c2r[kp] * inv, c2i[kp] * inv, Gkp, Hkp);
        Gp[k] = Gk + Gkp;  Gm[k] = Gk - Gkp;
        Hp[k] = Hk + Hkp;  Hm[k] = Hk - Hkp;
    }

    // ---- inverse DFT: 4 outputs per n-pair, written straight to own LDS row ----
    float* row = &tile[t * PAD];
    const float Dp = G0 + G16, Dm = G0 - G16;

    {   // specials n = 0, 16, 8, 24
        const float GA = Gp[2] + Gp[4] + Gp[6];
        const float GB = Gp[1] + Gp[3] + Gp[5] + Gp[7];
        const float b8 = Dp + G8;
        row[0]  = b8 + GA + GB;
        row[16] = b8 + GA - GB;
        const float C8 = -Gp[2] + Gp[4] - Gp[6];
        const float S8 =  Hm[1] - Hm[3] + Hm[5] - Hm[7];
        const float t8 = b8 + C8;
        row[8]  = t8 - S8;
        row[24] = t8 + S8;
    }

    #pragma unroll
    for (int n = 1; n <= 7; ++n) {
        const bool nodd = (n & 1);
        const float g1 = nodd ? Gm[1] : Gp[1], g3 = nodd ? Gm[3] : Gp[3];
        const float g5 = nodd ? Gm[5] : Gp[5], g7 = nodd ? Gm[7] : Gp[7];
        const float g2 = nodd ? Gm[2] : Gp[2], g4 = nodd ? Gm[4] : Gp[4];
        const float g6 = nodd ? Gm[6] : Gp[6];
        const float h1 = nodd ? Hp[1] : Hm[1], h3 = nodd ? Hp[3] : Hm[3];
        const float h5 = nodd ? Hp[5] : Hm[5], h7 = nodd ? Hp[7] : Hm[7];
        const float h2 = nodd ? Hp[2] : Hm[2], h4 = nodd ? Hp[4] : Hm[4];
        const float h6 = nodd ? Hp[6] : Hm[6];

        const float CE = fmaf(CT[(2*n)&31], g2, fmaf(CT[(4*n)&31], g4, CT[(6*n)&31] * g6));
        const float CO = fmaf(CT[n&31], g1, fmaf(CT[(3*n)&31], g3,
                         fmaf(CT[(5*n)&31], g5, CT[(7*n)&31] * g7)));
        const float SE = fmaf(ST[(2*n)&31], h2, fmaf(ST[(4*n)&31], h4, ST[(6*n)&31] * h6));
        const float SO = fmaf(ST[n&31], h1, fmaf(ST[(3*n)&31], h3,
                         fmaf(ST[(5*n)&31], h5, ST[(7*n)&31] * h7)));

        const float a = CE + CO, b = CE - CO, c = SE + SO, d = SE - SO;
        float w1, w2;
        if (nodd) {                                   // Q=0, P = sin(pi*n/2)*H8
            const float P = ((n & 2) == 0) ? H8 : -H8;
            w1 = Dm - P;  w2 = Dm + P;
        } else {                                      // P=0, Q = cos(pi*n/2)*G8
            w1 = Dp + (((n & 2) == 0) ? G8 : -G8);
            w2 = w1;
        }
        row[n]      = w1 + a - c;
        row[32 - n] = w2 + a + c;
        row[16 - n] = w2 + b + d;
        row[16 + n] = w1 + b - d;
    }
    __syncthreads();

    // ---- coalesced LDS -> global store (nontemporal: never re-read) ----
    #pragma unroll
    for (int i = 0; i < 8; ++i) {
        const int ft = (i * RPB + t) * 4;
        const int r = ft >> 5, col = ft & 31;
        const float* p = &tile[r * PAD + col];
        f32x4 v;
        v.x = p[0]; v.y = p[1]; v.z = p[2]; v.w = p[3];
        __builtin_nontemporal_store(v, reinterpret_cast<f32x4*>(out + base + ft));
    }
}

extern "C" void kernel_launch(void* const* d_in, const int* in_sizes, int n_in,
                              void* d_out, int out_size, void* d_ws, size_t ws_size,
                              hipStream_t stream) {
    const float* x   = (const float*)d_in[0];
    const float* c1r = (const float*)d_in[1];
    const float* c1i = (const float*)d_in[2];
    const float* c2r = (const float*)d_in[3];
    const float* c2i = (const float*)d_in[4];
    float* out = (float*)d_out;

    const int total  = in_sizes[0];          // 64*8192*32 floats
    const int blocks = total / (RPB * NCH);  // 8192 single-wave blocks
    fcm_kernel<<<blocks, RPB, 0, stream>>>(x, c1r, c1i, c2r, c2i, out);
}

// Round 9
// 118.013 us; speedup vs baseline: 1.0642x; 1.0642x over previous
//
#include <hip/hip_runtime.h>
#include <math.h>

#define NCH 32
#define HALF 17
#define RPB 64      // rows per block = exactly one wave (no inter-wave barriers)
#define PAD 33      // LDS row pitch (floats): (t*33+c)%32 = (t+c)%32 -> conflict-free

// cos(2*pi*j/32), sin(2*pi*j/32)
constexpr float CT[32] = {
   1.0f,                 0.9807852804032304f,  0.9238795325112867f,  0.8314696123025452f,
   0.7071067811865476f,  0.5555702330196022f,  0.3826834323650898f,  0.1950903220161283f,
   0.0f,                -0.1950903220161283f, -0.3826834323650898f, -0.5555702330196022f,
  -0.7071067811865476f, -0.8314696123025452f, -0.9238795325112867f, -0.9807852804032304f,
  -1.0f,                -0.9807852804032304f, -0.9238795325112867f, -0.8314696123025452f,
  -0.7071067811865476f, -0.5555702330196022f, -0.3826834323650898f, -0.1950903220161283f,
   0.0f,                 0.1950903220161283f,  0.3826834323650898f,  0.5555702330196022f,
   0.7071067811865476f,  0.8314696123025452f,  0.9238795325112867f,  0.9807852804032304f
};
constexpr float ST[32] = {
   0.0f,                 0.1950903220161283f,  0.3826834323650898f,  0.5555702330196022f,
   0.7071067811865476f,  0.8314696123025452f,  0.9238795325112867f,  0.9807852804032304f,
   1.0f,                 0.9807852804032304f,  0.9238795325112867f,  0.8314696123025452f,
   0.7071067811865476f,  0.5555702330196022f,  0.3826834323650898f,  0.1950903220161283f,
   0.0f,                -0.1950903220161283f, -0.3826834323650898f, -0.5555702330196022f,
  -0.7071067811865476f, -0.8314696123025452f, -0.9238795325112867f, -0.9807852804032304f,
  -1.0f,                -0.9807852804032304f, -0.9238795325112867f, -0.8314696123025452f,
  -0.7071067811865476f, -0.5555702330196022f, -0.3826834323650898f, -0.1950903220161283f
};

// Complex nonlinearity for one bin. Bin value X = inv*(sr - i*si); the forward
// 1/sqrt(32) is pre-folded into (w1r,w1i); the inverse scale (2*inv for k=1..15,
// inv for DC/Nyquist) AND the 0.5 of cosh/sinh are pre-folded into (w2r,w2i).
__device__ __forceinline__ void cnonlin(float sr, float si,
    float w1r, float w1i, float w2r, float w2i, float& G, float& H)
{
    const float p = fmaf(sr, w1r, si * w1i);        // Re(X*cm1)   (note Xim = -inv*si)
    const float q = fmaf(sr, w1i, -(si * w1r));     // Im(X*cm1)
    float sp, cp;
    __sincosf(p, &sp, &cp);
    const float eq = __expf(q), en = __expf(-q);
    const float sA = sp * (eq + en);                // 2*sin(p)*cosh(q)
    const float sB = cp * (eq - en);                // 2*cos(p)*sinh(q)
    G = fmaf(sA, w2r, -(sB * w2i));
    H = fmaf(sA, w2i, sB * w2r);
}

// DC/Nyquist bins: si == 0 on input, and irfft only consumes the real part.
__device__ __forceinline__ float cnonlin_real(float sr,
    float w1r, float w1i, float w2r, float w2i)
{
    const float p = sr * w1r;
    const float q = sr * w1i;
    float sp, cp;
    __sincosf(p, &sp, &cp);
    const float eq = __expf(q), en = __expf(-q);
    return fmaf(sp * (eq + en), w2r, -((cp * (eq - en)) * w2i));
}

__global__ __launch_bounds__(RPB, 3) void fcm_kernel(
    const float* __restrict__ x,
    const float* __restrict__ c1r, const float* __restrict__ c1i,
    const float* __restrict__ c2r, const float* __restrict__ c2i,
    float* __restrict__ out)
{
    __shared__ float tile[RPB * PAD];
    const int t = threadIdx.x;
    const long long base = (long long)blockIdx.x * (RPB * NCH);
    const float inv = 0.17677669529663687f;          // 1/sqrt(32)

    // ---- coalesced global -> LDS staging (float4 per lane) ----
    #pragma unroll
    for (int i = 0; i < 8; ++i) {
        const int ft = (i * RPB + t) * 4;
        float4 v = *reinterpret_cast<const float4*>(x + base + ft);
        const int row = ft >> 5, col = ft & 31;
        float* p = &tile[row * PAD + col];
        p[0] = v.x; p[1] = v.y; p[2] = v.z; p[3] = v.w;
    }
    __syncthreads();

    // ---- each thread owns one row of 32 channels ----
    float xr[NCH];
    #pragma unroll
    for (int j = 0; j < NCH; ++j) xr[j] = tile[t * PAD + j];

    // symmetric combos (halves the DFT inner loops)
    float ev[16], od[16];
    #pragma unroll
    for (int m = 1; m <= 15; ++m) {
        ev[m] = xr[m] + xr[32 - m];
        od[m] = xr[m] - xr[32 - m];
    }
    const float xp = xr[0] + xr[16], xm = xr[0] - xr[16];
    const float e8 = ev[8], o8 = od[8];
    float ep[8], em[8], opp[8], om[8];               // m = 1..7 used
    #pragma unroll
    for (int m = 1; m <= 7; ++m) {
        ep[m]  = ev[m] + ev[16 - m];
        em[m]  = ev[m] - ev[16 - m];
        opp[m] = od[m] + od[16 - m];
        om[m]  = od[m] - od[16 - m];
    }

    // ---- forward DFT (streamed) + nonlinearity -> combined inverse inputs ----
    float Gp[8], Gm[8], Hp[8], Hm[8];
    float G0, G16, G8, H8;

    {   // specials k = 0, 16, 8 (bins 0/16 real; Xim unused by irfft there)
        const float A  = ep[2] + ep[4] + ep[6];
        const float B  = ep[1] + ep[3] + ep[5] + ep[7];
        const float b0 = xp + e8;
        const float sr0  = b0 + A + B;
        const float sr16 = b0 + A - B;
        G0  = cnonlin_real(sr0,  c1r[0]  * inv, c1i[0]  * inv,
                           c2r[0]  * (0.5f * inv), c2i[0]  * (0.5f * inv));
        G16 = cnonlin_real(sr16, c1r[16] * inv, c1i[16] * inv,
                           c2r[16] * (0.5f * inv), c2i[16] * (0.5f * inv));
        const float sr8 = b0 - ep[2] + ep[4] - ep[6];
        const float si8 = om[1] - om[3] + om[5] - om[7];
        cnonlin(sr8, si8, c1r[8] * inv, c1i[8] * inv,
                c2r[8] * inv, c2i[8] * inv, G8, H8);
    }

    // pairs (k, 16-k), k = 1..7: shared even-m/odd-m partial sums serve both bins
    #pragma unroll
    for (int k = 1; k <= 7; ++k) {
        const int kp = 16 - k;
        const bool kodd = (k & 1);
        const float u1 = kodd ? em[1] : ep[1],  u3 = kodd ? em[3] : ep[3];
        const float u5 = kodd ? em[5] : ep[5],  u7 = kodd ? em[7] : ep[7];
        const float u2 = kodd ? em[2] : ep[2],  u4 = kodd ? em[4] : ep[4];
        const float u6 = kodd ? em[6] : ep[6];
        const float v1 = kodd ? opp[1] : om[1], v3 = kodd ? opp[3] : om[3];
        const float v5 = kodd ? opp[5] : om[5], v7 = kodd ? opp[7] : om[7];
        const float v2 = kodd ? opp[2] : om[2], v4 = kodd ? opp[4] : om[4];
        const float v6 = kodd ? opp[6] : om[6];

        const float SrE = fmaf(CT[(2*k)&31], u2, fmaf(CT[(4*k)&31], u4, CT[(6*k)&31] * u6));
        const float SrO = fmaf(CT[k&31], u1, fmaf(CT[(3*k)&31], u3,
                          fmaf(CT[(5*k)&31], u5, CT[(7*k)&31] * u7)));
        const float SiE = fmaf(ST[(2*k)&31], v2, fmaf(ST[(4*k)&31], v4, ST[(6*k)&31] * v6));
        const float SiO = fmaf(ST[k&31], v1, fmaf(ST[(3*k)&31], v3,
                          fmaf(ST[(5*k)&31], v5, ST[(7*k)&31] * v7)));

        // base: odd k -> x0-x16 (cos(pi*k/2)=0); even k -> x0+x16 +/- e8
        const float tb = kodd ? xm : (xp + (((k & 2) == 0) ? e8 : -e8));
        float SiEO  = SiE + SiO;
        float SiOmE = SiO - SiE;
        if (kodd) {                                   // sin(pi*k/2)*o8 term
            const float s8 = ((k & 2) == 0) ? o8 : -o8;
            SiEO  += s8;
            SiOmE -= s8;
        }
        const float srk  = tb + SrE + SrO;
        const float srkp = tb + (SrE - SrO);

        float Gk, Hk, Gkp, Hkp;
        cnonlin(srk,  SiEO,  c1r[k]  * inv, c1i[k]  * inv,
                c2r[k]  * inv, c2i[k]  * inv, Gk,  Hk);
        cnonlin(srkp, SiOmE, c1r[kp] * inv, c1i[kp] * inv,
                c2r[kp] * inv, c2i[kp] * inv, Gkp, Hkp);
        Gp[k] = Gk + Gkp;  Gm[k] = Gk - Gkp;
        Hp[k] = Hk + Hkp;  Hm[k] = Hk - Hkp;
    }

    // ---- inverse DFT: 4 outputs per n-pair, written straight to own LDS row ----
    float* row = &tile[t * PAD];
    const float Dp = G0 + G16, Dm = G0 - G16;

    {   // specials n = 0, 16, 8, 24
        const float GA = Gp[2] + Gp[4] + Gp[6];
        const float GB = Gp[1] + Gp[3] + Gp[5] + Gp[7];
        const float b8 = Dp + G8;
        row[0]  = b8 + GA + GB;
        row[16] = b8 + GA - GB;
        const float C8 = -Gp[2] + Gp[4] - Gp[6];
        const float S8 =  Hm[1] - Hm[3] + Hm[5] - Hm[7];
        const float t8 = b8 + C8;
        row[8]  = t8 - S8;
        row[24] = t8 + S8;
    }

    #pragma unroll
    for (int n = 1; n <= 7; ++n) {
        const bool nodd = (n & 1);
        const float g1 = nodd ? Gm[1] : Gp[1], g3 = nodd ? Gm[3] : Gp[3];
        const float g5 = nodd ? Gm[5] : Gp[5], g7 = nodd ? Gm[7] : Gp[7];
        const float g2 = nodd ? Gm[2] : Gp[2], g4 = nodd ? Gm[4] : Gp[4];
        const float g6 = nodd ? Gm[6] : Gp[6];
        const float h1 = nodd ? Hp[1] : Hm[1], h3 = nodd ? Hp[3] : Hm[3];
        const float h5 = nodd ? Hp[5] : Hm[5], h7 = nodd ? Hp[7] : Hm[7];
        const float h2 = nodd ? Hp[2] : Hm[2], h4 = nodd ? Hp[4] : Hm[4];
        const float h6 = nodd ? Hp[6] : Hm[6];

        const float CE = fmaf(CT[(2*n)&31], g2, fmaf(CT[(4*n)&31], g4, CT[(6*n)&31] * g6));
        const float CO = fmaf(CT[n&31], g1, fmaf(CT[(3*n)&31], g3,
                         fmaf(CT[(5*n)&31], g5, CT[(7*n)&31] * g7)));
        const float SE = fmaf(ST[(2*n)&31], h2, fmaf(ST[(4*n)&31], h4, ST[(6*n)&31] * h6));
        const float SO = fmaf(ST[n&31], h1, fmaf(ST[(3*n)&31], h3,
                         fmaf(ST[(5*n)&31], h5, ST[(7*n)&31] * h7)));

        const float a = CE + CO, b = CE - CO, c = SE + SO, d = SE - SO;
        float w1, w2;
        if (nodd) {                                   // Q=0, P = sin(pi*n/2)*H8
            const float P = ((n & 2) == 0) ? H8 : -H8;
            w1 = Dm - P;  w2 = Dm + P;
        } else {                                      // P=0, Q = cos(pi*n/2)*G8
            w1 = Dp + (((n & 2) == 0) ? G8 : -G8);
            w2 = w1;
        }
        row[n]      = w1 + a - c;
        row[32 - n] = w2 + a + c;
        row[16 - n] = w2 + b + d;
        row[16 + n] = w1 + b - d;
    }
    __syncthreads();

    // ---- coalesced LDS -> global store ----
    #pragma unroll
    for (int i = 0; i < 8; ++i) {
        const int ft = (i * RPB + t) * 4;
        const int r = ft >> 5, col = ft & 31;
        const float* p = &tile[r * PAD + col];
        float4 v;
        v.x = p[0]; v.y = p[1]; v.z = p[2]; v.w = p[3];
        *reinterpret_cast<float4*>(out + base + ft) = v;
    }
}

extern "C" void kernel_launch(void* const* d_in, const int* in_sizes, int n_in,
                              void* d_out, int out_size, void* d_ws, size_t ws_size,
                              hipStream_t stream) {
    const float* x   = (const float*)d_in[0];
    const float* c1r = (const float*)d_in[1];
    const float* c1i = (const float*)d_in[2];
    const float* c2r = (const float*)d_in[3];
    const float* c2i = (const float*)d_in[4];
    float* out = (float*)d_out;

    const int total  = in_sizes[0];          // 64*8192*32 floats
    const int blocks = total / (RPB * NCH);  // 8192 single-wave blocks
    fcm_kernel<<<blocks, RPB, 0, stream>>>(x, c1r, c1i, c2r, c2i, out);
}